// Round 9
// baseline (567.597 us; speedup 1.0000x reference)
//
#include <hip/hip_runtime.h>
#include <hip/hip_bf16.h>
#include <stdint.h>

#define M_DIM 8192
#define IN_F  4096
#define OUT_F 4096
#define NFP   256
#define NTT   36              // byte-tiles of 128B: 32 i8 + 4 bf16 tail
#define NTI8  32

typedef __attribute__((ext_vector_type(4)))  int   v4i;
typedef __attribute__((ext_vector_type(8)))  short short8;
typedef __attribute__((ext_vector_type(4)))  float f32x4;

__device__ __forceinline__ void stage16(const void* g, void* l) {
    __builtin_amdgcn_global_load_lds(
        (const __attribute__((address_space(1))) int*)g,
        (__attribute__((address_space(3))) int*)l,
        16, 0, 0);
}

#define SB() __builtin_amdgcn_sched_barrier(0)
#define BARRIER() do { SB(); __builtin_amdgcn_s_barrier(); SB(); } while (0)

// ---------------------------------------------------------------------------
// Kernel 1: per-row quantization (verified R6-R8).
//   qx  : M x IN_F int8  (0 at outlier cols)
//   acts: M x NFP bf16   (x[:,ind]/x_scale, pre-divided)
// ---------------------------------------------------------------------------
__global__ __launch_bounds__(256)
void quant_rows(const float* __restrict__ x,
                const int* __restrict__ ind,
                char* __restrict__ qx,
                __hip_bfloat16* __restrict__ acts,
                float* __restrict__ xscale)
{
    __shared__ short omap[IN_F];
    __shared__ float red[4];
    __shared__ float s_xs;

    const int t = threadIdx.x;
    const int row = blockIdx.x;

    #pragma unroll
    for (int i = 0; i < IN_F / 256; ++i) omap[t + i * 256] = -1;
    __syncthreads();
    omap[ind[t]] = (short)t;
    __syncthreads();

    const float* xr = x + (size_t)row * IN_F + t * 16;
    float v[16];
    #pragma unroll
    for (int j = 0; j < 4; ++j) {
        float4 f = *(const float4*)(xr + j * 4);
        v[j*4+0] = f.x; v[j*4+1] = f.y; v[j*4+2] = f.z; v[j*4+3] = f.w;
    }
    short om[16];
    #pragma unroll
    for (int j = 0; j < 16; ++j) om[j] = omap[t * 16 + j];

    float m_nz = 0.f;
    #pragma unroll
    for (int j = 0; j < 16; ++j) {
        float a = fabsf(v[j]);
        if (om[j] < 0) m_nz = fmaxf(m_nz, a);
    }
    #pragma unroll
    for (int off = 32; off > 0; off >>= 1)
        m_nz = fmaxf(m_nz, __shfl_down(m_nz, off));
    if ((t & 63) == 0) red[t >> 6] = m_nz;
    __syncthreads();
    if (t == 0) {
        float a = fmaxf(fmaxf(red[0], red[1]), fmaxf(red[2], red[3]));
        xscale[row] = a / 127.0f;
        s_xs = (a > 0.f) ? (a / 127.0f) : 1.0f;
    }
    __syncthreads();
    const float xs = s_xs;

    union { char c[16]; int4 q; } u;
    #pragma unroll
    for (int j = 0; j < 16; ++j) {
        if (om[j] >= 0) {
            acts[(size_t)row * NFP + om[j]] = __float2bfloat16(v[j] / xs);
            u.c[j] = 0;
        } else {
            float r = rintf(v[j] / xs);               // half-to-even == jnp.round
            r = fminf(fmaxf(r, -128.f), 127.f);
            u.c[j] = (char)(int)r;
        }
    }
    *(int4*)(qx + (size_t)row * IN_F + t * 16) = u.q;
}

// ---------------------------------------------------------------------------
// Kernel 2: weight int32 -> int8 (exact) + outlier gather -> bf16 (verified).
// ---------------------------------------------------------------------------
__global__ __launch_bounds__(256)
void conv_w(const int* __restrict__ qw, const int* __restrict__ ind,
            char* __restrict__ qb, __hip_bfloat16* __restrict__ wob)
{
    const int n = blockIdx.x;
    const int t = threadIdx.x;
    const int* src = qw + (size_t)n * IN_F + t * 16;
    union { char c[16]; int4 q; } u;
    #pragma unroll
    for (int j = 0; j < 4; ++j) {
        int4 raw = *(const int4*)(src + j * 4);
        u.c[j*4+0] = (char)raw.x; u.c[j*4+1] = (char)raw.y;
        u.c[j*4+2] = (char)raw.z; u.c[j*4+3] = (char)raw.w;
    }
    *(int4*)(qb + (size_t)n * IN_F + t * 16) = u.q;
    wob[(size_t)n * NFP + t] = __float2bfloat16((float)qw[(size_t)n * IN_F + ind[t]]);
}

// ---------------------------------------------------------------------------
// Kernel 3: R5's proven 256x256 8-phase structure (47% MfmaUtil, 0 conflicts),
// element type swapped to BYTES: 32 i8 tiles (mfma_i32_16x16x64_i8, exact) +
// in-register i32->f32 convert + 4 bf16 outlier tail tiles (same byte geom).
// 8 waves (2M x 4N), byte-tile = 128B of K. LDS 128KB: 2 bufs x {Ah0,Ah1,
// Bh0,Bh1} x 16KB. Phases/tile: {8,4,8,4} ds_read_b128 + stage {A(t+1)h0,
// A(t+1)h1, -, B(t+2)h0+h1}; counted vmcnt(4) once per tile.
// ---------------------------------------------------------------------------
#define LOADA(MB, KK) \
    { _Pragma("unroll") for (int i = 0; i < 4; ++i) \
        af[i] = *(const v4i*)&Abuf[(((MB)+i)*16 + fr)*128 + ((((KK)*64) + kq4*16) ^ rsw)]; }

#define LOADB(KK) \
    { _Pragma("unroll") for (int n = 0; n < 4; ++n) \
        bf[n] = *(const v4i*)&Bbuf[(wn1*64 + n*16 + fr)*128 + ((((KK)*64) + kq4*16) ^ rsw)]; }

#define MFMA16_I8(MB) \
    { _Pragma("unroll") for (int i = 0; i < 4; ++i) \
      _Pragma("unroll") for (int n = 0; n < 4; ++n) { \
        v4i ai = __builtin_bit_cast(v4i, acc[(MB)+i][n]); \
        ai = __builtin_amdgcn_mfma_i32_16x16x64_i8(af[i], bf[n], ai, 0, 0, 0); \
        acc[(MB)+i][n] = __builtin_bit_cast(f32x4, ai); } }

#define MFMA16_BF(MB) \
    { _Pragma("unroll") for (int i = 0; i < 4; ++i) \
      _Pragma("unroll") for (int n = 0; n < 4; ++n) \
        acc[(MB)+i][n] = __builtin_amdgcn_mfma_f32_16x16x32_bf16( \
            __builtin_bit_cast(short8, af[i]), __builtin_bit_cast(short8, bf[n]), \
            acc[(MB)+i][n], 0, 0, 0); }

__global__ __launch_bounds__(512, 2)
void gemm_mix(const char* __restrict__ Aq,  // qx   M x 4096 i8
              const char* __restrict__ Bq,  // qb   N x 4096 i8
              const char* __restrict__ Ab,  // acts M x 512B bf16
              const char* __restrict__ Bb,  // wob  N x 512B bf16
              const float* __restrict__ rscale,
              const float* __restrict__ cscale,
              const float* __restrict__ bias,
              float* __restrict__ out)
{
    __shared__ __attribute__((aligned(16))) char smem[131072];   // 128 KiB

    const int tid = threadIdx.x;
    const int wv = tid >> 6, lane = tid & 63;
    const int wm = wv >> 2, wn = wv & 3;
    const int wn1 = wn & 1, whb = wn >> 1;
    const int fr = lane & 15, kq4 = lane >> 4;
    const int rsw = (fr & 7) << 4;               // read-side XOR (bytes)

    // XCD-aware bijective swizzle (512 blocks, 512 % 8 == 0)
    const int bid = blockIdx.x;
    const int lin = (bid & 7) * 64 + (bid >> 3);
    const int bm = (lin & 31) * 256;             // 32 M-tiles
    const int bn = (lin >> 5) * 256;             // 16 N-tiles

    // staging: thread covers rows srow, srow+64 of a 128-row half; 16B cols
    const int srow = tid >> 3;                   // 0..63
    const int scb  = ((tid & 7) * 16) ^ ((srow & 7) << 4);   // pre-swizzled

    auto stageA = [&](int T, int h, int c) {
        const char* src; size_t st;
        if (T < NTI8) { src = Aq + (size_t)(bm + h * 128 + srow) * IN_F
                            + T * 128 + scb;                  st = IN_F; }
        else          { src = Ab + (size_t)(bm + h * 128 + srow) * (NFP * 2)
                            + (T - NTI8) * 128 + scb;         st = NFP * 2; }
        char* dst = smem + c * 65536 + h * 16384 + wv * 1024;
        stage16(src, dst);
        stage16(src + 64 * st, dst + 8192);
    };
    auto stageB = [&](int T, int h, int c) {
        const char* src; size_t st;
        if (T < NTI8) { src = Bq + (size_t)(bn + h * 128 + srow) * IN_F
                            + T * 128 + scb;                  st = IN_F; }
        else          { src = Bb + (size_t)(bn + h * 128 + srow) * (NFP * 2)
                            + (T - NTI8) * 128 + scb;         st = NFP * 2; }
        char* dst = smem + c * 65536 + 32768 + h * 16384 + wv * 1024;
        stage16(src, dst);
        stage16(src + 64 * st, dst + 8192);
    };

    f32x4 acc[8][4] = {};
    v4i af[4], bf[4];

    // prologue: tile0 {B,A} + tile1 {B}; newest 4 loads may stay in flight
    stageB(0, 0, 0); stageB(0, 1, 0);
    stageA(0, 0, 0); stageA(0, 1, 0);
    stageB(1, 0, 1); stageB(1, 1, 1);
    SB();
    asm volatile("s_waitcnt vmcnt(4)" ::: "memory");
    BARRIER();

    for (int t = 0; t < NTT; ++t) {
        const int c = t & 1;
        const char* Abuf = smem + c * 65536 + wm * 16384;
        const char* Bbuf = smem + c * 65536 + 32768 + whb * 16384;

        if (t == NTI8) {                 // exact i32 -> f32, once, in-register
            #pragma unroll
            for (int m = 0; m < 8; ++m)
                #pragma unroll
                for (int n = 0; n < 4; ++n) {
                    v4i ai = __builtin_bit_cast(v4i, acc[m][n]);
                    f32x4 f;
                    #pragma unroll
                    for (int r = 0; r < 4; ++r) f[r] = (float)ai[r];
                    acc[m][n] = f;
                }
        }
        const bool i8ph = (t < NTI8);

        // ---- P1: B k0 + A m0-3 k0 (8 reads); stage A(t+1)h0 -> buf c^1 ----
        LOADB(0);
        LOADA(0, 0);
        if (t + 1 < NTT) stageA(t + 1, 0, c ^ 1);
        BARRIER();
        __builtin_amdgcn_s_setprio(1);
        if (i8ph) { MFMA16_I8(0); } else { MFMA16_BF(0); }
        __builtin_amdgcn_s_setprio(0);
        BARRIER();

        // ---- P2: A m4-7 k0 (4 reads); stage A(t+1)h1 ----
        LOADA(4, 0);
        if (t + 1 < NTT) stageA(t + 1, 1, c ^ 1);
        BARRIER();
        __builtin_amdgcn_s_setprio(1);
        if (i8ph) { MFMA16_I8(4); } else { MFMA16_BF(4); }
        __builtin_amdgcn_s_setprio(0);
        BARRIER();

        // ---- P3: B k1 + A m0-3 k1 (8 reads); no stage ----
        LOADB(1);
        LOADA(0, 1);
        BARRIER();
        __builtin_amdgcn_s_setprio(1);
        if (i8ph) { MFMA16_I8(0); } else { MFMA16_BF(0); }
        __builtin_amdgcn_s_setprio(0);
        BARRIER();

        // ---- P4: A m4-7 k1 (4 reads); stage B(t+2) (B-regions freed @P3) ----
        LOADA(4, 1);
        if (t + 2 < NTT) { stageB(t + 2, 0, c); stageB(t + 2, 1, c); }
        BARRIER();
        __builtin_amdgcn_s_setprio(1);
        if (i8ph) { MFMA16_I8(4); } else { MFMA16_BF(4); }
        __builtin_amdgcn_s_setprio(0);
        SB();
        if (t < NTT - 2)       asm volatile("s_waitcnt vmcnt(4)" ::: "memory");
        else if (t == NTT - 2) asm volatile("s_waitcnt vmcnt(0)" ::: "memory");
        BARRIER();
    }

    // epilogue: 16x16 C/D layout col = lane&15, row = (lane>>4)*4 + reg [m89]
    #pragma unroll
    for (int m = 0; m < 8; ++m) {
        const int rbase = bm + wm * 128 + m * 16 + kq4 * 4;
        #pragma unroll
        for (int n = 0; n < 4; ++n) {
            const int col = bn + wn * 64 + n * 16 + fr;
            const float csv = cscale[col];
            const float badd = bias[col];
            #pragma unroll
            for (int r = 0; r < 4; ++r) {
                const int row = rbase + r;
                out[(size_t)row * OUT_F + col] =
                    acc[m][n][r] * rscale[row] * csv + badd;
            }
        }
    }
}

// ---------------------------------------------------------------------------
extern "C" void kernel_launch(void* const* d_in, const int* in_sizes, int n_in,
                              void* d_out, int out_size, void* d_ws, size_t ws_size,
                              hipStream_t stream)
{
    const float* x         = (const float*)d_in[0];
    const int*   q_weight  = (const int*)d_in[1];    // int32 on device
    const float* scale_col = (const float*)d_in[2];
    const float* bias      = (const float*)d_in[3];
    const int*   ind       = (const int*)d_in[4];
    float*       out       = (float*)d_out;

    // workspace (~54 MB)
    char*           qx   = (char*)d_ws;                              // M x IN_F i8
    char*           qb   = qx + (size_t)M_DIM * IN_F;                // OUT_F x IN_F i8
    __hip_bfloat16* acts = (__hip_bfloat16*)(qb + (size_t)OUT_F * IN_F);  // M x NFP
    __hip_bfloat16* wob  = acts + (size_t)M_DIM * NFP;               // OUT_F x NFP
    float*          xs   = (float*)(wob + (size_t)OUT_F * NFP);      // M

    const size_t need = (size_t)((char*)(xs + M_DIM) - (char*)d_ws);
    if (ws_size < need) return;

    quant_rows<<<dim3(M_DIM), dim3(256), 0, stream>>>(x, ind, qx, acts, xs);
    conv_w<<<dim3(OUT_F), dim3(256), 0, stream>>>(q_weight, ind, qb, wob);

    gemm_mix<<<dim3((M_DIM / 256) * (OUT_F / 256)), dim3(512), 0, stream>>>(
        qx, qb, (const char*)acts, (const char*)wob,
        xs, scale_col, bias, out);
}

// Round 10
// 209.918 us; speedup vs baseline: 2.7039x; 2.7039x over previous
//
#include <hip/hip_runtime.h>
#include <hip/hip_bf16.h>
#include <stdint.h>

#define M_DIM 8192
#define IN_F  4096
#define OUT_F 4096
#define NFP   256
#define NTI8  32              // i8 byte-tiles (4096 B / 128 B)
#define NTB   4               // bf16 tail byte-tiles (512 B / 128 B)

typedef __attribute__((ext_vector_type(4)))  int   v4i;
typedef __attribute__((ext_vector_type(8)))  short short8;
typedef __attribute__((ext_vector_type(4)))  float f32x4;

__device__ __forceinline__ void stage16(const void* g, void* l) {
    __builtin_amdgcn_global_load_lds(
        (const __attribute__((address_space(1))) int*)g,
        (__attribute__((address_space(3))) int*)l,
        16, 0, 0);
}

#define SB() __builtin_amdgcn_sched_barrier(0)
#define BARRIER() do { SB(); __builtin_amdgcn_s_barrier(); SB(); } while (0)

// ---------------------------------------------------------------------------
// Kernel 1: per-row quantization (verified R6-R9).
// ---------------------------------------------------------------------------
__global__ __launch_bounds__(256)
void quant_rows(const float* __restrict__ x,
                const int* __restrict__ ind,
                char* __restrict__ qx,
                __hip_bfloat16* __restrict__ acts,
                float* __restrict__ xscale)
{
    __shared__ short omap[IN_F];
    __shared__ float red[4];
    __shared__ float s_xs;

    const int t = threadIdx.x;
    const int row = blockIdx.x;

    #pragma unroll
    for (int i = 0; i < IN_F / 256; ++i) omap[t + i * 256] = -1;
    __syncthreads();
    omap[ind[t]] = (short)t;
    __syncthreads();

    const float* xr = x + (size_t)row * IN_F + t * 16;
    float v[16];
    #pragma unroll
    for (int j = 0; j < 4; ++j) {
        float4 f = *(const float4*)(xr + j * 4);
        v[j*4+0] = f.x; v[j*4+1] = f.y; v[j*4+2] = f.z; v[j*4+3] = f.w;
    }
    short om[16];
    #pragma unroll
    for (int j = 0; j < 16; ++j) om[j] = omap[t * 16 + j];

    float m_nz = 0.f;
    #pragma unroll
    for (int j = 0; j < 16; ++j) {
        float a = fabsf(v[j]);
        if (om[j] < 0) m_nz = fmaxf(m_nz, a);
    }
    #pragma unroll
    for (int off = 32; off > 0; off >>= 1)
        m_nz = fmaxf(m_nz, __shfl_down(m_nz, off));
    if ((t & 63) == 0) red[t >> 6] = m_nz;
    __syncthreads();
    if (t == 0) {
        float a = fmaxf(fmaxf(red[0], red[1]), fmaxf(red[2], red[3]));
        xscale[row] = a / 127.0f;
        s_xs = (a > 0.f) ? (a / 127.0f) : 1.0f;
    }
    __syncthreads();
    const float xs = s_xs;

    union { char c[16]; int4 q; } u;
    #pragma unroll
    for (int j = 0; j < 16; ++j) {
        if (om[j] >= 0) {
            acts[(size_t)row * NFP + om[j]] = __float2bfloat16(v[j] / xs);
            u.c[j] = 0;
        } else {
            float r = rintf(v[j] / xs);               // half-to-even == jnp.round
            r = fminf(fmaxf(r, -128.f), 127.f);
            u.c[j] = (char)(int)r;
        }
    }
    *(int4*)(qx + (size_t)row * IN_F + t * 16) = u.q;
}

// ---------------------------------------------------------------------------
// Kernel 2: weight int32 -> int8 (exact) + outlier gather -> bf16 (verified).
// ---------------------------------------------------------------------------
__global__ __launch_bounds__(256)
void conv_w(const int* __restrict__ qw, const int* __restrict__ ind,
            char* __restrict__ qb, __hip_bfloat16* __restrict__ wob)
{
    const int n = blockIdx.x;
    const int t = threadIdx.x;
    const int* src = qw + (size_t)n * IN_F + t * 16;
    union { char c[16]; int4 q; } u;
    #pragma unroll
    for (int j = 0; j < 4; ++j) {
        int4 raw = *(const int4*)(src + j * 4);
        u.c[j*4+0] = (char)raw.x; u.c[j*4+1] = (char)raw.y;
        u.c[j*4+2] = (char)raw.z; u.c[j*4+3] = (char)raw.w;
    }
    *(int4*)(qb + (size_t)n * IN_F + t * 16) = u.q;
    wob[(size_t)n * NFP + t] = __float2bfloat16((float)qw[(size_t)n * IN_F + ind[t]]);
}

// ---------------------------------------------------------------------------
// Kernel 3: 256x256 8-phase GEMM, TWO MONOMORPHIC LOOPS (R9 post-mortem:
// dual-type loop body broke the R5 schedule; each loop is now pure).
//   Loop 1: 32 i8 byte-tiles, mfma_i32_16x16x64_i8, v4i acc, exact.
//   Convert i32 -> f32 once.
//   Loop 2: 4 bf16 byte-tiles over acts/wob (outliers, pre-divided by xscale).
// Geometry (byte-identical to R5's proven 47%-MfmaUtil kernel): 8 waves
// (2M x 4N), byte-tile = 128B K, LDS 128KB = 2 bufs x {Ah0,Ah1,Bh0,Bh1} x
// 16KB; phases {8,4,8,4} ds_read_b128 + stage {A(t+1)h0, A(t+1)h1, -,
// B(t+2)h0+h1}; counted vmcnt(4) once per tile; XOR swizzle both-sides.
// ---------------------------------------------------------------------------
#define LOADA8(MB, KK) \
    { _Pragma("unroll") for (int i = 0; i < 4; ++i) \
        af[i] = *(const v4i*)&Abuf[(((MB)+i)*16 + fr)*128 + ((((KK)*64) + kq4*16) ^ rsw)]; }
#define LOADB8(KK) \
    { _Pragma("unroll") for (int n = 0; n < 4; ++n) \
        bf4[n] = *(const v4i*)&Bbuf[(wn1*64 + n*16 + fr)*128 + ((((KK)*64) + kq4*16) ^ rsw)]; }
#define MFMA_I8(MB) \
    { _Pragma("unroll") for (int i = 0; i < 4; ++i) \
      _Pragma("unroll") for (int n = 0; n < 4; ++n) \
        acci[(MB)+i][n] = __builtin_amdgcn_mfma_i32_16x16x64_i8(af[i], bf4[n], acci[(MB)+i][n], 0, 0, 0); }

#define LOADAB(MB, KK) \
    { _Pragma("unroll") for (int i = 0; i < 4; ++i) \
        ab[i] = *(const short8*)&Abuf[(((MB)+i)*16 + fr)*128 + ((((KK)*64) + kq4*16) ^ rsw)]; }
#define LOADBB(KK) \
    { _Pragma("unroll") for (int n = 0; n < 4; ++n) \
        bb[n] = *(const short8*)&Bbuf[(wn1*64 + n*16 + fr)*128 + ((((KK)*64) + kq4*16) ^ rsw)]; }
#define MFMA_BF(MB) \
    { _Pragma("unroll") for (int i = 0; i < 4; ++i) \
      _Pragma("unroll") for (int n = 0; n < 4; ++n) \
        accf[(MB)+i][n] = __builtin_amdgcn_mfma_f32_16x16x32_bf16(ab[i], bb[n], accf[(MB)+i][n], 0, 0, 0); }

__global__ __launch_bounds__(512, 2)
void gemm_mix(const char* __restrict__ Aq,  // qx   M x 4096 i8
              const char* __restrict__ Bq,  // qb   N x 4096 i8
              const char* __restrict__ Ab,  // acts M x 512B bf16
              const char* __restrict__ Bb,  // wob  N x 512B bf16
              const float* __restrict__ rscale,
              const float* __restrict__ cscale,
              const float* __restrict__ bias,
              float* __restrict__ out)
{
    __shared__ __attribute__((aligned(16))) char smem[131072];   // 128 KiB

    const int tid = threadIdx.x;
    const int wv = tid >> 6, lane = tid & 63;
    const int wm = wv >> 2, wn = wv & 3;
    const int wn1 = wn & 1, whb = wn >> 1;
    const int fr = lane & 15, kq4 = lane >> 4;
    const int rsw = (fr & 7) << 4;               // read-side XOR (bytes)

    // XCD-aware bijective swizzle (512 blocks, 512 % 8 == 0)
    const int bid = blockIdx.x;
    const int lin = (bid & 7) * 64 + (bid >> 3);
    const int bm = (lin & 31) * 256;
    const int bn = (lin >> 5) * 256;

    const int srow = tid >> 3;                   // 0..63
    const int scb  = ((tid & 7) * 16) ^ ((srow & 7) << 4);   // pre-swizzled col

    // ---- branch-free stage lambdas (i8 main) ----
    auto stageA8 = [&](int T, int h, int c) {
        const char* src = Aq + (size_t)(bm + h * 128 + srow) * IN_F + T * 128 + scb;
        char* dst = smem + c * 65536 + h * 16384 + wv * 1024;
        stage16(src, dst);
        stage16(src + (size_t)64 * IN_F, dst + 8192);
    };
    auto stageB8 = [&](int T, int h, int c) {
        const char* src = Bq + (size_t)(bn + h * 128 + srow) * IN_F + T * 128 + scb;
        char* dst = smem + c * 65536 + 32768 + h * 16384 + wv * 1024;
        stage16(src, dst);
        stage16(src + (size_t)64 * IN_F, dst + 8192);
    };
    // ---- branch-free stage lambdas (bf16 tail, row stride 512 B) ----
    auto stageAb = [&](int T, int h, int c) {
        const char* src = Ab + (size_t)(bm + h * 128 + srow) * 512 + T * 128 + scb;
        char* dst = smem + c * 65536 + h * 16384 + wv * 1024;
        stage16(src, dst);
        stage16(src + (size_t)64 * 512, dst + 8192);
    };
    auto stageBb = [&](int T, int h, int c) {
        const char* src = Bb + (size_t)(bn + h * 128 + srow) * 512 + T * 128 + scb;
        char* dst = smem + c * 65536 + 32768 + h * 16384 + wv * 1024;
        stage16(src, dst);
        stage16(src + (size_t)64 * 512, dst + 8192);
    };

    // =========================== Loop 1: int8 ===========================
    v4i acci[8][4] = {};
    {
        v4i af[4], bf4[4];

        stageB8(0, 0, 0); stageB8(0, 1, 0);
        stageA8(0, 0, 0); stageA8(0, 1, 0);
        stageB8(1, 0, 1); stageB8(1, 1, 1);
        SB();
        asm volatile("s_waitcnt vmcnt(4)" ::: "memory");
        BARRIER();

        for (int t = 0; t < NTI8; ++t) {
            const int c = t & 1;
            const char* Abuf = smem + c * 65536 + wm * 16384;
            const char* Bbuf = smem + c * 65536 + 32768 + whb * 16384;

            // P1
            LOADB8(0);
            LOADA8(0, 0);
            if (t + 1 < NTI8) stageA8(t + 1, 0, c ^ 1);
            BARRIER();
            __builtin_amdgcn_s_setprio(1);
            MFMA_I8(0);
            __builtin_amdgcn_s_setprio(0);
            BARRIER();
            // P2
            LOADA8(4, 0);
            if (t + 1 < NTI8) stageA8(t + 1, 1, c ^ 1);
            BARRIER();
            __builtin_amdgcn_s_setprio(1);
            MFMA_I8(4);
            __builtin_amdgcn_s_setprio(0);
            BARRIER();
            // P3
            LOADB8(1);
            LOADA8(0, 1);
            BARRIER();
            __builtin_amdgcn_s_setprio(1);
            MFMA_I8(0);
            __builtin_amdgcn_s_setprio(0);
            BARRIER();
            // P4
            LOADA8(4, 1);
            if (t + 2 < NTI8) { stageB8(t + 2, 0, c); stageB8(t + 2, 1, c); }
            BARRIER();
            __builtin_amdgcn_s_setprio(1);
            MFMA_I8(4);
            __builtin_amdgcn_s_setprio(0);
            SB();
            if (t < NTI8 - 2)       asm volatile("s_waitcnt vmcnt(4)" ::: "memory");
            else if (t == NTI8 - 2) asm volatile("s_waitcnt vmcnt(0)" ::: "memory");
            BARRIER();
        }
    }

    // exact i32 -> f32 convert, per fragment
    f32x4 accf[8][4];
    #pragma unroll
    for (int m = 0; m < 8; ++m)
        #pragma unroll
        for (int n = 0; n < 4; ++n) {
            const v4i q = acci[m][n];
            f32x4 f;
            #pragma unroll
            for (int r = 0; r < 4; ++r) f[r] = (float)q[r];
            accf[m][n] = f;
        }

    // ========================== Loop 2: bf16 tail ==========================
    {
        short8 ab[4], bb[4];

        stageBb(0, 0, 0); stageBb(0, 1, 0);
        stageAb(0, 0, 0); stageAb(0, 1, 0);
        stageBb(1, 0, 1); stageBb(1, 1, 1);
        SB();
        asm volatile("s_waitcnt vmcnt(4)" ::: "memory");
        BARRIER();

        for (int t = 0; t < NTB; ++t) {
            const int c = t & 1;
            const char* Abuf = smem + c * 65536 + wm * 16384;
            const char* Bbuf = smem + c * 65536 + 32768 + whb * 16384;

            // P1
            LOADBB(0);
            LOADAB(0, 0);
            if (t + 1 < NTB) stageAb(t + 1, 0, c ^ 1);
            BARRIER();
            __builtin_amdgcn_s_setprio(1);
            MFMA_BF(0);
            __builtin_amdgcn_s_setprio(0);
            BARRIER();
            // P2
            LOADAB(4, 0);
            if (t + 1 < NTB) stageAb(t + 1, 1, c ^ 1);
            BARRIER();
            __builtin_amdgcn_s_setprio(1);
            MFMA_BF(4);
            __builtin_amdgcn_s_setprio(0);
            BARRIER();
            // P3
            LOADBB(1);
            LOADAB(0, 1);
            BARRIER();
            __builtin_amdgcn_s_setprio(1);
            MFMA_BF(0);
            __builtin_amdgcn_s_setprio(0);
            BARRIER();
            // P4
            LOADAB(4, 1);
            if (t + 2 < NTB) { stageBb(t + 2, 0, c); stageBb(t + 2, 1, c); }
            BARRIER();
            __builtin_amdgcn_s_setprio(1);
            MFMA_BF(4);
            __builtin_amdgcn_s_setprio(0);
            SB();
            if (t < NTB - 2)       asm volatile("s_waitcnt vmcnt(4)" ::: "memory");
            else if (t == NTB - 2) asm volatile("s_waitcnt vmcnt(0)" ::: "memory");
            BARRIER();
        }
    }

    // epilogue: 16x16 C/D layout col = lane&15, row = (lane>>4)*4 + reg [m89]
    #pragma unroll
    for (int m = 0; m < 8; ++m) {
        const int rbase = bm + wm * 128 + m * 16 + kq4 * 4;
        #pragma unroll
        for (int n = 0; n < 4; ++n) {
            const int col = bn + wn * 64 + n * 16 + fr;
            const float csv = cscale[col];
            const float badd = bias[col];
            #pragma unroll
            for (int r = 0; r < 4; ++r) {
                const int row = rbase + r;
                out[(size_t)row * OUT_F + col] =
                    accf[m][n][r] * rscale[row] * csv + badd;
            }
        }
    }
}

// ---------------------------------------------------------------------------
extern "C" void kernel_launch(void* const* d_in, const int* in_sizes, int n_in,
                              void* d_out, int out_size, void* d_ws, size_t ws_size,
                              hipStream_t stream)
{
    const float* x         = (const float*)d_in[0];
    const int*   q_weight  = (const int*)d_in[1];    // int32 on device
    const float* scale_col = (const float*)d_in[2];
    const float* bias      = (const float*)d_in[3];
    const int*   ind       = (const int*)d_in[4];
    float*       out       = (float*)d_out;

    // workspace (~54 MB)
    char*           qx   = (char*)d_ws;                              // M x IN_F i8
    char*           qb   = qx + (size_t)M_DIM * IN_F;                // OUT_F x IN_F i8
    __hip_bfloat16* acts = (__hip_bfloat16*)(qb + (size_t)OUT_F * IN_F);  // M x NFP
    __hip_bfloat16* wob  = acts + (size_t)M_DIM * NFP;               // OUT_F x NFP
    float*          xs   = (float*)(wob + (size_t)OUT_F * NFP);      // M

    const size_t need = (size_t)((char*)(xs + M_DIM) - (char*)d_ws);
    if (ws_size < need) return;

    quant_rows<<<dim3(M_DIM), dim3(256), 0, stream>>>(x, ind, qx, acts, xs);
    conv_w<<<dim3(OUT_F), dim3(256), 0, stream>>>(q_weight, ind, qb, wob);

    gemm_mix<<<dim3((M_DIM / 256) * (OUT_F / 256)), dim3(512), 0, stream>>>(
        qx, qb, (const char*)acts, (const char*)wob,
        xs, scale_col, bias, out);
}